// Round 1
// baseline (19833.066 us; speedup 1.0000x reference)
//
#include <hip/hip_runtime.h>
#include <hip/hip_bf16.h>

// LSTMOutputProj: 2-layer LSTM (H=1024) over 128 sequential steps, BT=512 rows.
// Persistent kernel. Rows are independent -> grid splits into 4 independent
// groups of 64 blocks (128 rows each); barriers are group-scoped (64 arrivals).
// 2 barriers/step (was 3): logits+cur are recomputed per-block (local MFMA,
// hi/lo-split bf16 Wo) so no cross-block cur exchange is needed.
//   Phase 1: logits(s-1)+cur(s-1) local + layer0 cell (MFMA)   -> barrier
//   Phase 2: layer1 cell (MFMA, K=2048)                        -> barrier

#define BTROWS 512
#define HD     1024
#define G4     4096
#define NSTEPS 128
#define NOUTC  33

typedef __attribute__((ext_vector_type(8))) short s8v;
typedef __attribute__((ext_vector_type(4))) float f4v;
typedef unsigned int u32;

__device__ __forceinline__ float fsig(float x)  { return 1.0f / (1.0f + __expf(-x)); }
__device__ __forceinline__ float ftanh(float x) { return 2.0f / (1.0f + __expf(-2.0f * x)) - 1.0f; }

__device__ __forceinline__ short f2bf(float x) {
  union { __hip_bfloat16 b; short s; } u; u.b = __float2bfloat16(x); return u.s;
}
__device__ __forceinline__ float bf2f(short s) {
  union { __hip_bfloat16 b; short v; } u; u.v = s; return __bfloat162float(u.b);
}

// ---------------- group barrier (agent scope, safe across XCD L2s) ------------
__device__ __forceinline__ void gridbar(u32* bar, u32 target) {
  __syncthreads();
  if (threadIdx.x == 0) {
    __threadfence();  // release: make this block's stores agent-visible
    __hip_atomic_fetch_add(bar, 1u, __ATOMIC_RELAXED, __HIP_MEMORY_SCOPE_AGENT);
    while (__hip_atomic_load(bar, __ATOMIC_RELAXED, __HIP_MEMORY_SCOPE_AGENT) < target) {
      __builtin_amdgcn_s_sleep(1);
    }
    __threadfence();  // acquire: invalidate stale lines
  }
  __syncthreads();
}

// ---------------- precompute: transpose -> fragment-linearized bf16 -----------
// src: fp32 [1024 x 4096] (rows k, cols n). dst tile (ntile,kchunk) is 1KB:
// lane l holds n=16*ntile+(l&15), k=32*kchunk+(l>>4)*8 .. +8  (16B per lane).
__global__ __launch_bounds__(256) void transpose_frag_kernel(
    const float* __restrict__ src, short* __restrict__ dst_hi,
    short* __restrict__ dst_lo, int NK, int koff) {
  __shared__ float St[64][65];
  int n0 = (blockIdx.x & 63) * 64;
  int k0 = (blockIdx.x >> 6) * 64;
  int t = threadIdx.x;
  int nl = t & 63, kl = t >> 6;
#pragma unroll
  for (int it = 0; it < 16; ++it) {
    int k = kl + it * 4;
    St[k][nl] = src[(size_t)(k0 + k) * 4096 + n0 + nl];
  }
  __syncthreads();
  int lane = t & 63, w = t >> 6;
  for (int it = 0; it < 2; ++it) {
    int sub = it * 4 + w;  // 0..7 : 4 ntiles x 2 kchunks
    int nt = sub >> 1, kc = sub & 1;
    int nloc = nt * 16 + (lane & 15);
    int kbase = kc * 32 + (lane >> 4) * 8;
    float v[8];
#pragma unroll
    for (int ii = 0; ii < 8; ++ii) v[ii] = St[kbase + ii][nloc];
    s8v hv;
#pragma unroll
    for (int ii = 0; ii < 8; ++ii) hv[ii] = f2bf(v[ii]);
    size_t ntg = (size_t)(n0 / 16 + nt);
    size_t kcg = (size_t)(k0 / 32 + kc + koff);
    size_t off = (ntg * (size_t)NK + kcg) * 512 + (size_t)lane * 8;
    *(s8v*)(dst_hi + off) = hv;
    if (dst_lo) {
      s8v lv;
#pragma unroll
      for (int ii = 0; ii < 8; ++ii) lv[ii] = f2bf(v[ii] - bf2f(hv[ii]));
      *(s8v*)(dst_lo + off) = lv;
    }
  }
}

// ---------------- precompute: cond = x @ Wc + bc  (fp32, split to bf16 hi/lo) -
__global__ __launch_bounds__(256) void cond_kernel(
    const float* __restrict__ x, const float* __restrict__ Wc,
    const float* __restrict__ bc, short* __restrict__ cond_hi,
    short* __restrict__ cond_lo) {
  __shared__ float xs[8][512];
  int rb = (blockIdx.x >> 2) * 8;
  int cb = (blockIdx.x & 3) * 256;
  int t = threadIdx.x;
  for (int i = t; i < 8 * 512; i += 256)
    xs[i >> 9][i & 511] = x[(size_t)(rb + (i >> 9)) * 512 + (i & 511)];
  __syncthreads();
  float acc[8] = {0, 0, 0, 0, 0, 0, 0, 0};
  for (int k = 0; k < 512; ++k) {
    float w = Wc[(size_t)k * 1024 + cb + t];
#pragma unroll
    for (int rr = 0; rr < 8; ++rr) acc[rr] += xs[rr][k] * w;
  }
  float bcv = bc[cb + t];
#pragma unroll
  for (int rr = 0; rr < 8; ++rr) {
    float v = acc[rr] + bcv;
    short hi = f2bf(v);
    cond_hi[(size_t)(rb + rr) * 1024 + cb + t] = hi;
    cond_lo[(size_t)(rb + rr) * 1024 + cb + t] = f2bf(v - bf2f(hi));
  }
}

// ---------------- precompute: vec0, Wf, b1vec ---------------------------------
__global__ __launch_bounds__(256) void vecs_kernel(
    const float* __restrict__ Wih0, const float* __restrict__ bi,
    const float* __restrict__ Wi, const float* __restrict__ bih0,
    const float* __restrict__ bhh0, const float* __restrict__ bih1,
    const float* __restrict__ bhh1, float* __restrict__ vec0,
    float* __restrict__ Wf, float* __restrict__ b1vec) {
  int n = blockIdx.x * 256 + threadIdx.x;  // 0..4095
  float v0 = 0.f, w0 = 0.f, w1 = 0.f;
  for (int k = 0; k < 1024; ++k) {
    float w = Wih0[(size_t)k * 4096 + n];
    v0 += bi[k] * w;
    w0 += Wi[k] * w;
    w1 += Wi[1024 + k] * w;
  }
  vec0[n] = v0 + bih0[n] + bhh0[n];
  Wf[2 * n + 0] = w0;
  Wf[2 * n + 1] = w1;
  b1vec[n] = bih1[n] + bhh1[n];
}

// ---------------- precompute: Wo -> fragment-linearized bf16 hi/lo, N=48 pad --
__global__ __launch_bounds__(64) void wof_kernel(const float* __restrict__ Wo,
                                                 short* __restrict__ hi,
                                                 short* __restrict__ lo) {
  int nt = blockIdx.x >> 5;   // 0..2
  int kc = blockIdx.x & 31;   // 0..31
  int lane = threadIdx.x;     // 0..63
  int ch = nt * 16 + (lane & 15);
  int kb = kc * 32 + (lane >> 4) * 8;
  s8v hv, lv;
#pragma unroll
  for (int ii = 0; ii < 8; ++ii) {
    float v = (ch < NOUTC) ? Wo[(size_t)(kb + ii) * NOUTC + ch] : 0.f;
    short h = f2bf(v);
    hv[ii] = h;
    lv[ii] = f2bf(v - bf2f(h));
  }
  size_t off = ((size_t)(nt * 32 + kc)) * 512 + (size_t)lane * 8;
  *(s8v*)(hi + off) = hv;
  *(s8v*)(lo + off) = lv;
}

// ---------------- precompute: const0 = cond @ Wih0[H:] + vec0  (split bf16) ---
__global__ __launch_bounds__(512) void const0_kernel(
    const short* __restrict__ cond_hi, const short* __restrict__ cond_lo,
    const short* __restrict__ WTc_hi, const short* __restrict__ WTc_lo,
    const float* __restrict__ vec0, float* __restrict__ const0) {
  int j = blockIdx.x & 63, i = blockIdx.x >> 6;
  int w = threadIdx.x >> 6, lane = threadIdx.x & 63;
  int quad = lane >> 4, l16 = lane & 15;
  int rowA = i * 128 + w * 16 + l16;
  int rowC = i * 128 + w * 16 + quad * 4;
  int hid = j * 16 + l16;
  const short* ah = cond_hi + (size_t)rowA * 1024 + quad * 8;
  const short* al = cond_lo + (size_t)rowA * 1024 + quad * 8;
  f4v acc[4];
#pragma unroll
  for (int g = 0; g < 4; ++g) acc[g] = (f4v){0.f, 0.f, 0.f, 0.f};
#pragma unroll 2
  for (int kk = 0; kk < 32; ++kk) {
    s8v avh = *(const s8v*)(ah + kk * 32);
    s8v avl = *(const s8v*)(al + kk * 32);
#pragma unroll
    for (int g = 0; g < 4; ++g) {
      size_t off = ((size_t)(g * 64 + j) * 32 + kk) * 512 + (size_t)lane * 8;
      s8v bh = *(const s8v*)(WTc_hi + off);
      s8v bl = *(const s8v*)(WTc_lo + off);
      acc[g] = __builtin_amdgcn_mfma_f32_16x16x32_bf16(avh, bh, acc[g], 0, 0, 0);
      acc[g] = __builtin_amdgcn_mfma_f32_16x16x32_bf16(avh, bl, acc[g], 0, 0, 0);
      acc[g] = __builtin_amdgcn_mfma_f32_16x16x32_bf16(avl, bh, acc[g], 0, 0, 0);
    }
  }
#pragma unroll
  for (int g = 0; g < 4; ++g) {
    float vv = vec0[g * 1024 + hid];
#pragma unroll
    for (int p = 0; p < 4; ++p) {
      int r = rowC + p;
      const0[(size_t)r * G4 + g * 1024 + hid] = acc[g][p] + vv;
    }
  }
}

// ---------------- logits tile for one wave's 16 rows --------------------------
// ah: A-fragment base for this wave's h1 rows (already incl. bank+1024+quad8).
// Writes lt[16][34] = logits + bias for rows (quad*4+p), chans 0..32.
__device__ __forceinline__ void logits_tile(
    const short* __restrict__ ah, const short* __restrict__ WoFh,
    const short* __restrict__ WoFl, int lane, int quad, int l16,
    float bo0, float bo1, float bo2, float (*lt)[34]) {
  f4v la0 = {0.f, 0.f, 0.f, 0.f};
  f4v la1 = {0.f, 0.f, 0.f, 0.f};
  f4v la2 = {0.f, 0.f, 0.f, 0.f};
#pragma unroll 4
  for (int kk = 0; kk < 32; ++kk) {
    s8v av = *(const s8v*)(ah + kk * 32);
    const short* bh = WoFh + (size_t)kk * 512 + (size_t)lane * 8;
    const short* bl = WoFl + (size_t)kk * 512 + (size_t)lane * 8;
    la0 = __builtin_amdgcn_mfma_f32_16x16x32_bf16(av, *(const s8v*)bh, la0, 0, 0, 0);
    la0 = __builtin_amdgcn_mfma_f32_16x16x32_bf16(av, *(const s8v*)bl, la0, 0, 0, 0);
    la1 = __builtin_amdgcn_mfma_f32_16x16x32_bf16(av, *(const s8v*)(bh + 32 * 512), la1, 0, 0, 0);
    la1 = __builtin_amdgcn_mfma_f32_16x16x32_bf16(av, *(const s8v*)(bl + 32 * 512), la1, 0, 0, 0);
    la2 = __builtin_amdgcn_mfma_f32_16x16x32_bf16(av, *(const s8v*)(bh + 64 * 512), la2, 0, 0, 0);
    la2 = __builtin_amdgcn_mfma_f32_16x16x32_bf16(av, *(const s8v*)(bl + 64 * 512), la2, 0, 0, 0);
  }
  int r0 = quad * 4;
#pragma unroll
  for (int p = 0; p < 4; ++p) {
    lt[r0 + p][l16] = la0[p] + bo0;
    lt[r0 + p][16 + l16] = la1[p] + bo1;
    if (l16 == 0) lt[r0 + p][32] = la2[p] + bo2;
  }
}

// ---------------- main persistent kernel --------------------------------------
__global__ __launch_bounds__(512) void lstm_main(
    const short* __restrict__ WT0, const short* __restrict__ WT1,
    const float* __restrict__ const0, const float* __restrict__ Wf,
    const float* __restrict__ b1vec, const short* __restrict__ WoFh,
    const short* __restrict__ WoFl, const float* __restrict__ bo,
    const float* __restrict__ sos, float* __restrict__ out,
    short* __restrict__ hbuf, u32* __restrict__ bar) {
  int bid = blockIdx.x, tid = threadIdx.x;
  int j = bid & 63, i = bid >> 6;  // group i: 64 blocks, rows i*128..i*128+127
  int w = tid >> 6, lane = tid & 63;
  int quad = lane >> 4, l16 = lane & 15;
  int quad8 = quad * 8;
  __shared__ float lgl[8][16][34];  // per-wave logits tiles

  // zero this group's hbuf rows (both banks): 128 rows * 4096 shorts = 1 MB
  {
    uint4 z = {0u, 0u, 0u, 0u};
    uint4* hz = (uint4*)(hbuf + (size_t)i * 128 * G4);
    size_t tg = (size_t)j * 512 + tid;  // 0..32767
    hz[tg * 2 + 0] = z;
    hz[tg * 2 + 1] = z;
  }
  u32* gbar = bar + (size_t)i * 256;  // group counters 1 KB apart
  u32 snum = 0;
  ++snum; gridbar(gbar, snum * 64u);

  int rowA = i * 128 + w * 16 + l16;      // row for A-operand fragments
  int rowC = i * 128 + w * 16 + quad * 4; // base row for C/D + epilogue
  int hid = j * 16 + l16;

  // step-invariant per-thread loads
  float wfv[4][2], b1v[4], c0v[4][4];
#pragma unroll
  for (int g = 0; g < 4; ++g) {
    wfv[g][0] = Wf[(g * 1024 + hid) * 2 + 0];
    wfv[g][1] = Wf[(g * 1024 + hid) * 2 + 1];
    b1v[g] = b1vec[g * 1024 + hid];
#pragma unroll
    for (int p = 0; p < 4; ++p)
      c0v[g][p] = const0[(size_t)(rowC + p) * G4 + g * 1024 + hid];
  }
  size_t nb0[4], nb1[4];
#pragma unroll
  for (int g = 0; g < 4; ++g) {
    nb0[g] = (size_t)(g * 64 + j) * 32;
    nb1[g] = (size_t)(g * 64 + j) * 64;
  }
  float bo0 = bo[l16];
  float bo1 = bo[16 + l16];
  float bo2 = bo[32];
  float sos0 = sos[0], sos1 = sos[1];
  float c0s[4] = {0.f, 0.f, 0.f, 0.f};
  float c1s[4] = {0.f, 0.f, 0.f, 0.f};
  float cu0[4], cu1[4];

  for (int s = 0; s < NSTEPS; ++s) {
    int bank_r = (s & 1) * 2048;
    int bank_w = ((s + 1) & 1) * 2048;

    // ---- Phase 1a: logits(s-1) + cur(s-1), computed locally per block ----
    if (s == 0) {
#pragma unroll
      for (int p = 0; p < 4; ++p) { cu0[p] = sos0; cu1[p] = sos1; }
    } else {
      const short* ah1 = hbuf + (size_t)rowA * G4 + bank_r + 1024 + quad8;
      logits_tile(ah1, WoFh, WoFl, lane, quad, l16, bo0, bo1, bo2, lgl[w]);
      __syncthreads();
      // out-write: block j owns global rows i*128 + {2j, 2j+1}
      if (tid < 2 * NOUTC) {
        int rloc = (tid >= NOUTC) ? 1 : 0;
        int ch = tid - rloc * NOUTC;
        int rl = j * 2 + rloc;
        float v = lgl[rl >> 4][rl & 15][ch];
        int r = i * 128 + rl;
        out[((size_t)((r >> 6) * NOUTC + ch) * 64 + (r & 63)) * 128 + (s - 1)] = v;
      }
      // cur for this lane's 4 rows (rows quad*4+p of wave w's tile)
#pragma unroll
      for (int p = 0; p < 4; ++p) {
        int rl = quad * 4 + p;
        cu0[p] = (lgl[w][rl][0] > 0.0f) ? 1.0f : 0.0f;
        float mx = lgl[w][rl][1];
        int mi = 0;
        for (int v = 1; v < 32; ++v) {
          float t = lgl[w][rl][1 + v];
          if (t > mx) { mx = t; mi = v; }
        }
        cu1[p] = (float)mi * (1.0f / 31.0f);
      }
    }

    // ---- Phase 1b: layer 0  g0 = h0_prev @ Whh0 + const0 + cur@Wf ----
    {
      f4v acc[4];
#pragma unroll
      for (int g = 0; g < 4; ++g) acc[g] = (f4v){0.f, 0.f, 0.f, 0.f};
      const short* ap = hbuf + (size_t)rowA * G4 + bank_r + quad8;
#pragma unroll 4
      for (int kk = 0; kk < 32; ++kk) {
        s8v av = *(const s8v*)(ap + kk * 32);
#pragma unroll
        for (int g = 0; g < 4; ++g) {
          s8v bv = *(const s8v*)(WT0 + (nb0[g] + kk) * 512 + (size_t)lane * 8);
          acc[g] = __builtin_amdgcn_mfma_f32_16x16x32_bf16(av, bv, acc[g], 0, 0, 0);
        }
      }
#pragma unroll
      for (int p = 0; p < 4; ++p) {
        int r = rowC + p;
        float gi = acc[0][p] + c0v[0][p] + cu0[p] * wfv[0][0] + cu1[p] * wfv[0][1];
        float gf = acc[1][p] + c0v[1][p] + cu0[p] * wfv[1][0] + cu1[p] * wfv[1][1];
        float gg = acc[2][p] + c0v[2][p] + cu0[p] * wfv[2][0] + cu1[p] * wfv[2][1];
        float go = acc[3][p] + c0v[3][p] + cu0[p] * wfv[3][0] + cu1[p] * wfv[3][1];
        float cc = fsig(gf) * c0s[p] + fsig(gi) * ftanh(gg);
        c0s[p] = cc;
        hbuf[(size_t)r * G4 + bank_w + hid] = f2bf(fsig(go) * ftanh(cc));
      }
    }
    ++snum; gridbar(gbar, snum * 64u);

    // ---- Phase 2: layer 1  g1 = h0_new @ Wih1 + h1_prev @ Whh1 + b1 ----
    {
      f4v acc[4];
#pragma unroll
      for (int g = 0; g < 4; ++g) acc[g] = (f4v){0.f, 0.f, 0.f, 0.f};
      const short* ap0 = hbuf + (size_t)rowA * G4 + bank_w + quad8;         // h0 new
      const short* ap1 = hbuf + (size_t)rowA * G4 + bank_r + 1024 + quad8;  // h1 old
#pragma unroll 4
      for (int kk = 0; kk < 32; ++kk) {
        s8v av = *(const s8v*)(ap0 + kk * 32);
#pragma unroll
        for (int g = 0; g < 4; ++g) {
          s8v bv = *(const s8v*)(WT1 + (nb1[g] + kk) * 512 + (size_t)lane * 8);
          acc[g] = __builtin_amdgcn_mfma_f32_16x16x32_bf16(av, bv, acc[g], 0, 0, 0);
        }
      }
#pragma unroll 4
      for (int kk = 0; kk < 32; ++kk) {
        s8v av = *(const s8v*)(ap1 + kk * 32);
#pragma unroll
        for (int g = 0; g < 4; ++g) {
          s8v bv = *(const s8v*)(WT1 + (nb1[g] + 32 + kk) * 512 + (size_t)lane * 8);
          acc[g] = __builtin_amdgcn_mfma_f32_16x16x32_bf16(av, bv, acc[g], 0, 0, 0);
        }
      }
#pragma unroll
      for (int p = 0; p < 4; ++p) {
        int r = rowC + p;
        float gi = acc[0][p] + b1v[0];
        float gf = acc[1][p] + b1v[1];
        float gg = acc[2][p] + b1v[2];
        float go = acc[3][p] + b1v[3];
        float cc = fsig(gf) * c1s[p] + fsig(gi) * ftanh(gg);
        c1s[p] = cc;
        hbuf[(size_t)r * G4 + bank_w + 1024 + hid] = f2bf(fsig(go) * ftanh(cc));
      }
    }
    ++snum; gridbar(gbar, snum * 64u);
  }

  // final logits for s=127 (h1(127) sits in bank (128&1)=0)
  {
    const short* ah1 = hbuf + (size_t)rowA * G4 + 0 + 1024 + quad8;
    logits_tile(ah1, WoFh, WoFl, lane, quad, l16, bo0, bo1, bo2, lgl[w]);
    __syncthreads();
    if (tid < 2 * NOUTC) {
      int rloc = (tid >= NOUTC) ? 1 : 0;
      int ch = tid - rloc * NOUTC;
      int rl = j * 2 + rloc;
      float v = lgl[rl >> 4][rl & 15][ch];
      int r = i * 128 + rl;
      out[((size_t)((r >> 6) * NOUTC + ch) * 64 + (r & 63)) * 128 + (NSTEPS - 1)] = v;
    }
  }
}

// ---------------- host launch -------------------------------------------------
extern "C" void kernel_launch(void* const* d_in, const int* in_sizes, int n_in,
                              void* d_out, int out_size, void* d_ws, size_t ws_size,
                              hipStream_t stream) {
  (void)in_sizes; (void)n_in; (void)out_size; (void)ws_size;
  const float* x    = (const float*)d_in[0];
  const float* sos  = (const float*)d_in[1];
  const float* Wc   = (const float*)d_in[2];
  const float* bc   = (const float*)d_in[3];
  const float* Wi   = (const float*)d_in[4];
  const float* bi   = (const float*)d_in[5];
  const float* Wih0 = (const float*)d_in[6];
  const float* Whh0 = (const float*)d_in[7];
  const float* bih0 = (const float*)d_in[8];
  const float* bhh0 = (const float*)d_in[9];
  const float* Wih1 = (const float*)d_in[10];
  const float* Whh1 = (const float*)d_in[11];
  const float* bih1 = (const float*)d_in[12];
  const float* bhh1 = (const float*)d_in[13];
  const float* Wo   = (const float*)d_in[14];
  const float* bo   = (const float*)d_in[15];
  float* out = (float*)d_out;

  char* p = (char*)d_ws;
  short* WT0    = (short*)p; p += (size_t)256 * 32 * 512 * 2;  // 8 MB
  short* WT1    = (short*)p; p += (size_t)256 * 64 * 512 * 2;  // 16 MB
  short* WTc_hi = (short*)p; p += (size_t)256 * 32 * 512 * 2;  // 8 MB
  short* WTc_lo = (short*)p; p += (size_t)256 * 32 * 512 * 2;  // 8 MB
  float* const0 = (float*)p; p += (size_t)512 * 4096 * 4;      // 8 MB
  short* hbuf   = (short*)p; p += (size_t)512 * 4096 * 2;      // 4 MB
  short* cond_hi= (short*)p; p += (size_t)512 * 1024 * 2;      // 1 MB
  short* cond_lo= (short*)p; p += (size_t)512 * 1024 * 2;      // 1 MB
  float* vec0   = (float*)p; p += 4096 * 4;
  float* Wf     = (float*)p; p += 4096 * 2 * 4;
  float* b1vec  = (float*)p; p += 4096 * 4;
  short* WoFh   = (short*)p; p += (size_t)48 * 1024 * 2;       // 96 KB
  short* WoFl   = (short*)p; p += (size_t)48 * 1024 * 2;       // 96 KB
  u32*   bar    = (u32*)p;   p += 4096;                        // 4 group counters, 1KB apart

  hipMemsetAsync(bar, 0, 4096, stream);

  transpose_frag_kernel<<<1024, 256, 0, stream>>>(Whh0, WT0, nullptr, 32, 0);
  transpose_frag_kernel<<<1024, 256, 0, stream>>>(Wih1, WT1, nullptr, 64, 0);
  transpose_frag_kernel<<<1024, 256, 0, stream>>>(Whh1, WT1, nullptr, 64, 32);
  transpose_frag_kernel<<<1024, 256, 0, stream>>>(Wih0 + (size_t)1024 * 4096,
                                                  WTc_hi, WTc_lo, 32, 0);
  cond_kernel<<<256, 256, 0, stream>>>(x, Wc, bc, cond_hi, cond_lo);
  vecs_kernel<<<16, 256, 0, stream>>>(Wih0, bi, Wi, bih0, bhh0, bih1, bhh1,
                                      vec0, Wf, b1vec);
  wof_kernel<<<96, 64, 0, stream>>>(Wo, WoFh, WoFl);
  const0_kernel<<<256, 512, 0, stream>>>(cond_hi, cond_lo, WTc_hi, WTc_lo,
                                         vec0, const0);
  lstm_main<<<256, 512, 0, stream>>>(WT0, WT1, const0, Wf, b1vec, WoFh, WoFl,
                                     bo, sos, out, hbuf, bar);
}

// Round 4
// 12557.487 us; speedup vs baseline: 1.5794x; 1.5794x over previous
//
#include <hip/hip_runtime.h>
#include <hip/hip_bf16.h>

// LSTMOutputProj: 2-layer LSTM (H=1024) over 128 sequential steps, BT=512 rows.
// Persistent kernel. 8 INTRA-XCD groups: each XCD owns 64 rows, worked by 32
// blocks resident on that XCD (runtime XCC_ID claim). All h exchange stays
// inside one XCD's L2 -> NO fences, NO buffer_inv, weights stay L2/MALL-cached.
//   - h stores: global_store sc0 (write-through L1 -> L2, ack at vmcnt)
//   - h loads:  global_load  sc0 (bypass stale per-CU L1, hit fresh L2), 8-wide
//   - barrier:  vmcnt(0) + syncthreads + per-group atomic counter (same-XCD)
// 2 barriers/step; logits+cur recomputed locally per block.

#define G4     4096
#define NSTEPS 128
#define NOUTC  33

typedef __attribute__((ext_vector_type(8))) short s8v;
typedef __attribute__((ext_vector_type(4))) float f4v;
typedef unsigned int u32;
typedef unsigned long long u64;

__device__ __forceinline__ float fsig(float x)  { return 1.0f / (1.0f + __expf(-x)); }
__device__ __forceinline__ float ftanh(float x) { return 2.0f / (1.0f + __expf(-2.0f * x)) - 1.0f; }

__device__ __forceinline__ short f2bf(float x) {
  union { __hip_bfloat16 b; short s; } u; u.b = __float2bfloat16(x); return u.s;
}
__device__ __forceinline__ float bf2f(short s) {
  union { __hip_bfloat16 b; short v; } u; u.v = s; return __bfloat162float(u.b);
}

// 8 x 16B loads, L1-bypass (sc0), stride 64B; one vmcnt(0) for the batch.
__device__ __forceinline__ void ld8_sc0(const short* p, s8v* d) {
  asm volatile(
      "global_load_dwordx4 %0, %8, off sc0\n\t"
      "global_load_dwordx4 %1, %8, off offset:64 sc0\n\t"
      "global_load_dwordx4 %2, %8, off offset:128 sc0\n\t"
      "global_load_dwordx4 %3, %8, off offset:192 sc0\n\t"
      "global_load_dwordx4 %4, %8, off offset:256 sc0\n\t"
      "global_load_dwordx4 %5, %8, off offset:320 sc0\n\t"
      "global_load_dwordx4 %6, %8, off offset:384 sc0\n\t"
      "global_load_dwordx4 %7, %8, off offset:448 sc0\n\t"
      "s_waitcnt vmcnt(0)"
      : "=v"(d[0]), "=v"(d[1]), "=v"(d[2]), "=v"(d[3]),
        "=v"(d[4]), "=v"(d[5]), "=v"(d[6]), "=v"(d[7])
      : "v"(p)
      : "memory");
}

// 8B coherent store (write-through L1 -> L2)
__device__ __forceinline__ void st8_sc0(short* p, u64 v) {
  asm volatile("global_store_dwordx2 %0, %1, off sc0" :: "v"(p), "v"(v) : "memory");
}

// ---------------- intra-XCD group barrier (no cache maintenance) --------------
__device__ __forceinline__ void gridbar(u32* bar, u32 target) {
  asm volatile("s_waitcnt vmcnt(0)" ::: "memory");
  __syncthreads();
  if (threadIdx.x == 0) {
    __hip_atomic_fetch_add(bar, 1u, __ATOMIC_RELAXED, __HIP_MEMORY_SCOPE_AGENT);
    while (__hip_atomic_load(bar, __ATOMIC_RELAXED, __HIP_MEMORY_SCOPE_AGENT) < target) {
      __builtin_amdgcn_s_sleep(1);
    }
  }
  __syncthreads();
}

// ---------------- precompute: transpose -> fragment-linearized bf16 -----------
__global__ __launch_bounds__(256) void transpose_frag_kernel(
    const float* __restrict__ src, short* __restrict__ dst_hi,
    short* __restrict__ dst_lo, int NK, int koff) {
  __shared__ float St[64][65];
  int n0 = (blockIdx.x & 63) * 64;
  int k0 = (blockIdx.x >> 6) * 64;
  int t = threadIdx.x;
  int nl = t & 63, kl = t >> 6;
#pragma unroll
  for (int it = 0; it < 16; ++it) {
    int k = kl + it * 4;
    St[k][nl] = src[(size_t)(k0 + k) * 4096 + n0 + nl];
  }
  __syncthreads();
  int lane = t & 63, w = t >> 6;
  for (int it = 0; it < 2; ++it) {
    int sub = it * 4 + w;  // 0..7 : 4 ntiles x 2 kchunks
    int nt = sub >> 1, kc = sub & 1;
    int nloc = nt * 16 + (lane & 15);
    int kbase = kc * 32 + (lane >> 4) * 8;
    float v[8];
#pragma unroll
    for (int ii = 0; ii < 8; ++ii) v[ii] = St[kbase + ii][nloc];
    s8v hv;
#pragma unroll
    for (int ii = 0; ii < 8; ++ii) hv[ii] = f2bf(v[ii]);
    size_t ntg = (size_t)(n0 / 16 + nt);
    size_t kcg = (size_t)(k0 / 32 + kc + koff);
    size_t off = (ntg * (size_t)NK + kcg) * 512 + (size_t)lane * 8;
    *(s8v*)(dst_hi + off) = hv;
    if (dst_lo) {
      s8v lv;
#pragma unroll
      for (int ii = 0; ii < 8; ++ii) lv[ii] = f2bf(v[ii] - bf2f(hv[ii]));
      *(s8v*)(dst_lo + off) = lv;
    }
  }
}

// ---------------- precompute: cond = x @ Wc + bc  (fp32, split to bf16 hi/lo) -
__global__ __launch_bounds__(256) void cond_kernel(
    const float* __restrict__ x, const float* __restrict__ Wc,
    const float* __restrict__ bc, short* __restrict__ cond_hi,
    short* __restrict__ cond_lo) {
  __shared__ float xs[8][512];
  int rb = (blockIdx.x >> 2) * 8;
  int cb = (blockIdx.x & 3) * 256;
  int t = threadIdx.x;
  for (int i = t; i < 8 * 512; i += 256)
    xs[i >> 9][i & 511] = x[(size_t)(rb + (i >> 9)) * 512 + (i & 511)];
  __syncthreads();
  float acc[8] = {0, 0, 0, 0, 0, 0, 0, 0};
  for (int k = 0; k < 512; ++k) {
    float w = Wc[(size_t)k * 1024 + cb + t];
#pragma unroll
    for (int rr = 0; rr < 8; ++rr) acc[rr] += xs[rr][k] * w;
  }
  float bcv = bc[cb + t];
#pragma unroll
  for (int rr = 0; rr < 8; ++rr) {
    float v = acc[rr] + bcv;
    short hi = f2bf(v);
    cond_hi[(size_t)(rb + rr) * 1024 + cb + t] = hi;
    cond_lo[(size_t)(rb + rr) * 1024 + cb + t] = f2bf(v - bf2f(hi));
  }
}

// ---------------- precompute: vec0, Wf, b1vec ---------------------------------
__global__ __launch_bounds__(256) void vecs_kernel(
    const float* __restrict__ Wih0, const float* __restrict__ bi,
    const float* __restrict__ Wi, const float* __restrict__ bih0,
    const float* __restrict__ bhh0, const float* __restrict__ bih1,
    const float* __restrict__ bhh1, float* __restrict__ vec0,
    float* __restrict__ Wf, float* __restrict__ b1vec) {
  int n = blockIdx.x * 256 + threadIdx.x;  // 0..4095
  float v0 = 0.f, w0 = 0.f, w1 = 0.f;
  for (int k = 0; k < 1024; ++k) {
    float w = Wih0[(size_t)k * 4096 + n];
    v0 += bi[k] * w;
    w0 += Wi[k] * w;
    w1 += Wi[1024 + k] * w;
  }
  vec0[n] = v0 + bih0[n] + bhh0[n];
  Wf[2 * n + 0] = w0;
  Wf[2 * n + 1] = w1;
  b1vec[n] = bih1[n] + bhh1[n];
}

// ---------------- precompute: Wo -> fragment-linearized bf16 hi/lo, N=48 pad --
__global__ __launch_bounds__(64) void wof_kernel(const float* __restrict__ Wo,
                                                 short* __restrict__ hi,
                                                 short* __restrict__ lo) {
  int nt = blockIdx.x >> 5;   // 0..2
  int kc = blockIdx.x & 31;   // 0..31
  int lane = threadIdx.x;     // 0..63
  int ch = nt * 16 + (lane & 15);
  int kb = kc * 32 + (lane >> 4) * 8;
  s8v hv, lv;
#pragma unroll
  for (int ii = 0; ii < 8; ++ii) {
    float v = (ch < NOUTC) ? Wo[(size_t)(kb + ii) * NOUTC + ch] : 0.f;
    short h = f2bf(v);
    hv[ii] = h;
    lv[ii] = f2bf(v - bf2f(h));
  }
  size_t off = ((size_t)(nt * 32 + kc)) * 512 + (size_t)lane * 8;
  *(s8v*)(hi + off) = hv;
  *(s8v*)(lo + off) = lv;
}

// ---------------- precompute: const0 = cond @ Wih0[H:] + vec0  (split bf16) ---
__global__ __launch_bounds__(512) void const0_kernel(
    const short* __restrict__ cond_hi, const short* __restrict__ cond_lo,
    const short* __restrict__ WTc_hi, const short* __restrict__ WTc_lo,
    const float* __restrict__ vec0, float* __restrict__ const0) {
  int j = blockIdx.x & 63, i = blockIdx.x >> 6;
  int w = threadIdx.x >> 6, lane = threadIdx.x & 63;
  int quad = lane >> 4, l16 = lane & 15;
  int rowA = i * 128 + w * 16 + l16;
  int rowC = i * 128 + w * 16 + quad * 4;
  int hid = j * 16 + l16;
  const short* ah = cond_hi + (size_t)rowA * 1024 + quad * 8;
  const short* al = cond_lo + (size_t)rowA * 1024 + quad * 8;
  f4v acc[4];
#pragma unroll
  for (int g = 0; g < 4; ++g) acc[g] = (f4v){0.f, 0.f, 0.f, 0.f};
#pragma unroll 2
  for (int kk = 0; kk < 32; ++kk) {
    s8v avh = *(const s8v*)(ah + kk * 32);
    s8v avl = *(const s8v*)(al + kk * 32);
#pragma unroll
    for (int g = 0; g < 4; ++g) {
      size_t off = ((size_t)(g * 64 + j) * 32 + kk) * 512 + (size_t)lane * 8;
      s8v bh = *(const s8v*)(WTc_hi + off);
      s8v bl = *(const s8v*)(WTc_lo + off);
      acc[g] = __builtin_amdgcn_mfma_f32_16x16x32_bf16(avh, bh, acc[g], 0, 0, 0);
      acc[g] = __builtin_amdgcn_mfma_f32_16x16x32_bf16(avh, bl, acc[g], 0, 0, 0);
      acc[g] = __builtin_amdgcn_mfma_f32_16x16x32_bf16(avl, bh, acc[g], 0, 0, 0);
    }
  }
#pragma unroll
  for (int g = 0; g < 4; ++g) {
    float vv = vec0[g * 1024 + hid];
#pragma unroll
    for (int p = 0; p < 4; ++p) {
      int r = rowC + p;
      const0[(size_t)r * G4 + g * 1024 + hid] = acc[g][p] + vv;
    }
  }
}

// ---------------- logits half-tile for one wave's 16 rows ---------------------
// ch==0: channels 0..15 (ntile0) + channel 32 (ntile2); ch==1: channels 16..31.
__device__ __forceinline__ void logits_half(
    const short* __restrict__ ah, const short* __restrict__ WoFh,
    const short* __restrict__ WoFl, int lane, int ch, int quad, int l16,
    float boA, float bo2, float (*lt)[34]) {
  f4v la = {0.f, 0.f, 0.f, 0.f};
  f4v lb = {0.f, 0.f, 0.f, 0.f};
  const short* bAh = WoFh + (ch ? 32 * 512 : 0) + (size_t)lane * 8;
  const short* bAl = WoFl + (ch ? 32 * 512 : 0) + (size_t)lane * 8;
  const short* bBh = WoFh + 64 * 512 + (size_t)lane * 8;
  const short* bBl = WoFl + 64 * 512 + (size_t)lane * 8;
  s8v af[8];
  for (int kb = 0; kb < 4; ++kb) {
    ld8_sc0(ah + kb * 256, af);
#pragma unroll
    for (int kk = 0; kk < 8; ++kk) {
      int kg = kb * 8 + kk;
      la = __builtin_amdgcn_mfma_f32_16x16x32_bf16(af[kk], *(const s8v*)(bAh + (size_t)kg * 512), la, 0, 0, 0);
      la = __builtin_amdgcn_mfma_f32_16x16x32_bf16(af[kk], *(const s8v*)(bAl + (size_t)kg * 512), la, 0, 0, 0);
      if (ch == 0) {
        lb = __builtin_amdgcn_mfma_f32_16x16x32_bf16(af[kk], *(const s8v*)(bBh + (size_t)kg * 512), lb, 0, 0, 0);
        lb = __builtin_amdgcn_mfma_f32_16x16x32_bf16(af[kk], *(const s8v*)(bBl + (size_t)kg * 512), lb, 0, 0, 0);
      }
    }
  }
  int r0 = quad * 4;
#pragma unroll
  for (int p = 0; p < 4; ++p) {
    if (ch == 0) {
      lt[r0 + p][l16] = la[p] + boA;
      if (l16 == 0) lt[r0 + p][32] = lb[p] + bo2;
    } else {
      lt[r0 + p][16 + l16] = la[p] + boA;
    }
  }
}

// ---------------- main persistent kernel --------------------------------------
__global__ __launch_bounds__(512) void lstm_main(
    const short* __restrict__ WT0, const short* __restrict__ WT1,
    const float* __restrict__ const0, const float* __restrict__ Wf,
    const float* __restrict__ b1vec, const short* __restrict__ WoFh,
    const short* __restrict__ WoFl, const float* __restrict__ bo,
    const float* __restrict__ sos, float* __restrict__ out,
    short* __restrict__ hbuf, u32* __restrict__ bar) {
  int tid = threadIdx.x;
  // which XCD am I on?  (HW_REG_XCC_ID = hwreg 20, verified on MI355X)
  u32 xcc;
  asm volatile("s_getreg_b32 %0, hwreg(20, 0, 32)" : "=s"(xcc));
  xcc &= 7;
  __shared__ u32 sslot;
  if (tid == 0)
    sslot = __hip_atomic_fetch_add(&bar[xcc], 1u, __ATOMIC_RELAXED,
                                   __HIP_MEMORY_SCOPE_AGENT);
  __syncthreads();
  u32 jb = sslot;
  if (jb >= 32) return;  // surplus block on a full XCD
  u32* gbar = bar + 64 + (size_t)xcc * 64;

  int w = tid >> 6, lane = tid & 63;
  int rt = w & 3, ch = w >> 2;
  int quad = lane >> 4, l16 = lane & 15;
  int quad8 = quad * 8;
  int R0g = (int)xcc * 64;                 // group's first row
  int rowA = R0g + rt * 16 + l16;          // A-fragment row
  int rowC = R0g + rt * 16 + quad * 4;     // C/D + epilogue base row
  int hid = (int)jb * 32 + ch * 16 + l16;  // gate/h column

  __shared__ float lgl[4][16][34];  // per-row-tile logits
  __shared__ short hst[8][16][20];  // per-wave h repack

  // step-invariant per-thread loads
  float wfv[4][2], b1v[4], c0v[4][4];
  size_t nb0[4], nb1[4];
#pragma unroll
  for (int g = 0; g < 4; ++g) {
    wfv[g][0] = Wf[(g * 1024 + hid) * 2 + 0];
    wfv[g][1] = Wf[(g * 1024 + hid) * 2 + 1];
    b1v[g] = b1vec[g * 1024 + hid];
#pragma unroll
    for (int p = 0; p < 4; ++p)
      c0v[g][p] = const0[(size_t)(rowC + p) * G4 + g * 1024 + hid];
    int nt = g * 64 + (int)jb * 2 + ch;
    nb0[g] = (size_t)nt * 32;
    nb1[g] = (size_t)nt * 64;
  }
  float boA = ch ? bo[16 + l16] : bo[l16];
  float bo2 = bo[32];
  float sos0 = sos[0], sos1 = sos[1];
  float c0s[4] = {0.f, 0.f, 0.f, 0.f};
  float c1s[4] = {0.f, 0.f, 0.f, 0.f};
  float cu0[4], cu1[4];

  int rr = lane >> 2;       // repack row
  int cg = (lane & 3) * 4;  // repack col group (4 shorts = 8B)
  u32 snum = 0;

  for (int s = 0; s < NSTEPS; ++s) {
    int bank_r = (s & 1) * 2048;
    int bank_w = ((s + 1) & 1) * 2048;

    // ---- Phase 1a: logits(s-1) + cur(s-1), local ----
    if (s == 0) {
#pragma unroll
      for (int p = 0; p < 4; ++p) { cu0[p] = sos0; cu1[p] = sos1; }
    } else {
      const short* ah1 = hbuf + (size_t)rowA * G4 + bank_r + 1024 + quad8;
      logits_half(ah1, WoFh, WoFl, lane, ch, quad, l16, boA, bo2, lgl[rt]);
      __syncthreads();
      if (tid < 2 * NOUTC) {
        int rloc = (tid >= NOUTC) ? 1 : 0;
        int chn = tid - rloc * NOUTC;
        int rl = (int)jb * 2 + rloc;              // 0..63 within group
        float v = lgl[rl >> 4][rl & 15][chn];
        int r = R0g + rl;
        out[((size_t)((r >> 6) * NOUTC + chn) * 64 + (r & 63)) * 128 + (s - 1)] = v;
      }
#pragma unroll
      for (int p = 0; p < 4; ++p) {
        int rl = quad * 4 + p;
        cu0[p] = (lgl[rt][rl][0] > 0.0f) ? 1.0f : 0.0f;
        float mx = lgl[rt][rl][1];
        int mi = 0;
        for (int v = 1; v < 32; ++v) {
          float t = lgl[rt][rl][1 + v];
          if (t > mx) { mx = t; mi = v; }
        }
        cu1[p] = (float)mi * (1.0f / 31.0f);
      }
    }

    // ---- Phase 1b: layer 0  g0 = h0_prev @ Whh0 + const0 + cur@Wf ----
    {
      f4v acc[4];
#pragma unroll
      for (int g = 0; g < 4; ++g) acc[g] = (f4v){0.f, 0.f, 0.f, 0.f};
      if (s > 0) {  // h0_prev == 0 at s==0
        const short* ap = hbuf + (size_t)rowA * G4 + bank_r + quad8;
        s8v af[8];
        for (int kb = 0; kb < 4; ++kb) {
          ld8_sc0(ap + kb * 256, af);
#pragma unroll
          for (int kk = 0; kk < 8; ++kk) {
            int kg = kb * 8 + kk;
#pragma unroll
            for (int g = 0; g < 4; ++g) {
              s8v bv = *(const s8v*)(WT0 + (nb0[g] + kg) * 512 + (size_t)lane * 8);
              acc[g] = __builtin_amdgcn_mfma_f32_16x16x32_bf16(af[kk], bv, acc[g], 0, 0, 0);
            }
          }
        }
      }
#pragma unroll
      for (int p = 0; p < 4; ++p) {
        float gi = acc[0][p] + c0v[0][p] + cu0[p] * wfv[0][0] + cu1[p] * wfv[0][1];
        float gf = acc[1][p] + c0v[1][p] + cu0[p] * wfv[1][0] + cu1[p] * wfv[1][1];
        float gg = acc[2][p] + c0v[2][p] + cu0[p] * wfv[2][0] + cu1[p] * wfv[2][1];
        float go = acc[3][p] + c0v[3][p] + cu0[p] * wfv[3][0] + cu1[p] * wfv[3][1];
        float cc = fsig(gf) * c0s[p] + fsig(gi) * ftanh(gg);
        c0s[p] = cc;
        hst[w][quad * 4 + p][l16] = f2bf(fsig(go) * ftanh(cc));
      }
      u64 v = *(const u64*)&hst[w][rr][cg];
      st8_sc0(hbuf + (size_t)(R0g + rt * 16 + rr) * G4 + bank_w +
                  (int)jb * 32 + ch * 16 + cg, v);
    }
    ++snum; gridbar(gbar, snum * 32u);

    // ---- Phase 2: layer 1  g1 = h0_new @ Wih1 + h1_prev @ Whh1 + b1 ----
    {
      f4v acc[4];
#pragma unroll
      for (int g = 0; g < 4; ++g) acc[g] = (f4v){0.f, 0.f, 0.f, 0.f};
      const short* ap0 = hbuf + (size_t)rowA * G4 + bank_w + quad8;  // h0 new
      s8v af[8];
      for (int kb = 0; kb < 4; ++kb) {
        ld8_sc0(ap0 + kb * 256, af);
#pragma unroll
        for (int kk = 0; kk < 8; ++kk) {
          int kg = kb * 8 + kk;
#pragma unroll
          for (int g = 0; g < 4; ++g) {
            s8v bv = *(const s8v*)(WT1 + (nb1[g] + kg) * 512 + (size_t)lane * 8);
            acc[g] = __builtin_amdgcn_mfma_f32_16x16x32_bf16(af[kk], bv, acc[g], 0, 0, 0);
          }
        }
      }
      if (s > 0) {  // h1_prev == 0 at s==0
        const short* ap1 = hbuf + (size_t)rowA * G4 + bank_r + 1024 + quad8;
        for (int kb = 0; kb < 4; ++kb) {
          ld8_sc0(ap1 + kb * 256, af);
#pragma unroll
          for (int kk = 0; kk < 8; ++kk) {
            int kg = kb * 8 + kk;
#pragma unroll
            for (int g = 0; g < 4; ++g) {
              s8v bv = *(const s8v*)(WT1 + (nb1[g] + 32 + kg) * 512 + (size_t)lane * 8);
              acc[g] = __builtin_amdgcn_mfma_f32_16x16x32_bf16(af[kk], bv, acc[g], 0, 0, 0);
            }
          }
        }
      }
#pragma unroll
      for (int p = 0; p < 4; ++p) {
        float gi = acc[0][p] + b1v[0];
        float gf = acc[1][p] + b1v[1];
        float gg = acc[2][p] + b1v[2];
        float go = acc[3][p] + b1v[3];
        float cc = fsig(gf) * c1s[p] + fsig(gi) * ftanh(gg);
        c1s[p] = cc;
        hst[w][quad * 4 + p][l16] = f2bf(fsig(go) * ftanh(cc));
      }
      u64 v = *(const u64*)&hst[w][rr][cg];
      st8_sc0(hbuf + (size_t)(R0g + rt * 16 + rr) * G4 + bank_w + 1024 +
                  (int)jb * 32 + ch * 16 + cg, v);
    }
    ++snum; gridbar(gbar, snum * 32u);
  }

  // final logits for s=127 (h1(127) is in bank 0)
  {
    const short* ah1 = hbuf + (size_t)rowA * G4 + 0 + 1024 + quad8;
    logits_half(ah1, WoFh, WoFl, lane, ch, quad, l16, boA, bo2, lgl[rt]);
    __syncthreads();
    if (tid < 2 * NOUTC) {
      int rloc = (tid >= NOUTC) ? 1 : 0;
      int chn = tid - rloc * NOUTC;
      int rl = (int)jb * 2 + rloc;
      float v = lgl[rl >> 4][rl & 15][chn];
      int r = R0g + rl;
      out[((size_t)((r >> 6) * NOUTC + chn) * 64 + (r & 63)) * 128 + (NSTEPS - 1)] = v;
    }
  }
}

// ---------------- host launch -------------------------------------------------
extern "C" void kernel_launch(void* const* d_in, const int* in_sizes, int n_in,
                              void* d_out, int out_size, void* d_ws, size_t ws_size,
                              hipStream_t stream) {
  (void)in_sizes; (void)n_in; (void)out_size; (void)ws_size;
  const float* x    = (const float*)d_in[0];
  const float* sos  = (const float*)d_in[1];
  const float* Wc   = (const float*)d_in[2];
  const float* bc   = (const float*)d_in[3];
  const float* Wi   = (const float*)d_in[4];
  const float* bi   = (const float*)d_in[5];
  const float* Wih0 = (const float*)d_in[6];
  const float* Whh0 = (const float*)d_in[7];
  const float* bih0 = (const float*)d_in[8];
  const float* bhh0 = (const float*)d_in[9];
  const float* Wih1 = (const float*)d_in[10];
  const float* Whh1 = (const float*)d_in[11];
  const float* bih1 = (const float*)d_in[12];
  const float* bhh1 = (const float*)d_in[13];
  const float* Wo   = (const float*)d_in[14];
  const float* bo   = (const float*)d_in[15];
  float* out = (float*)d_out;

  char* p = (char*)d_ws;
  short* WT0    = (short*)p; p += (size_t)256 * 32 * 512 * 2;  // 8 MB
  short* WT1    = (short*)p; p += (size_t)256 * 64 * 512 * 2;  // 16 MB
  short* WTc_hi = (short*)p; p += (size_t)256 * 32 * 512 * 2;  // 8 MB
  short* WTc_lo = (short*)p; p += (size_t)256 * 32 * 512 * 2;  // 8 MB
  float* const0 = (float*)p; p += (size_t)512 * 4096 * 4;      // 8 MB
  short* hbuf   = (short*)p; p += (size_t)512 * 4096 * 2;      // 4 MB
  short* cond_hi= (short*)p; p += (size_t)512 * 1024 * 2;      // 1 MB
  short* cond_lo= (short*)p; p += (size_t)512 * 1024 * 2;      // 1 MB
  float* vec0   = (float*)p; p += 4096 * 4;
  float* Wf     = (float*)p; p += 4096 * 2 * 4;
  float* b1vec  = (float*)p; p += 4096 * 4;
  short* WoFh   = (short*)p; p += (size_t)48 * 1024 * 2;       // 96 KB
  short* WoFl   = (short*)p; p += (size_t)48 * 1024 * 2;       // 96 KB
  u32*   bar    = (u32*)p;   p += 4096;  // [0..7] XCD slot counters; +64: group barriers

  hipMemsetAsync(bar, 0, 4096, stream);

  transpose_frag_kernel<<<1024, 256, 0, stream>>>(Whh0, WT0, nullptr, 32, 0);
  transpose_frag_kernel<<<1024, 256, 0, stream>>>(Wih1, WT1, nullptr, 64, 0);
  transpose_frag_kernel<<<1024, 256, 0, stream>>>(Whh1, WT1, nullptr, 64, 32);
  transpose_frag_kernel<<<1024, 256, 0, stream>>>(Wih0 + (size_t)1024 * 4096,
                                                  WTc_hi, WTc_lo, 32, 0);
  cond_kernel<<<256, 256, 0, stream>>>(x, Wc, bc, cond_hi, cond_lo);
  vecs_kernel<<<16, 256, 0, stream>>>(Wih0, bi, Wi, bih0, bhh0, bih1, bhh1,
                                      vec0, Wf, b1vec);
  wof_kernel<<<96, 64, 0, stream>>>(Wo, WoFh, WoFl);
  const0_kernel<<<256, 512, 0, stream>>>(cond_hi, cond_lo, WTc_hi, WTc_lo,
                                         vec0, const0);
  lstm_main<<<2048, 512, 0, stream>>>(WT0, WT1, const0, Wf, b1vec, WoFh, WoFl,
                                      bo, sos, out, hbuf, bar);
}